// Round 1
// baseline (46.266 us; speedup 1.0000x reference)
//
#include <hip/hip_runtime.h>
#include <stdint.h>

#define SEQ 8192
#define NB  128
#define MAXP 4096
#define NT  256

__device__ __forceinline__ bool haszero8(uint64_t v) {
    return ((v - 0x0101010101010101ULL) & ~v & 0x8080808080808080ULL) != 0ULL;
}

__device__ __forceinline__ bool distinct8(uint64_t w) {
    // pairwise-distinct of 8 bytes via 4 rotations (covers all 28 pairs)
    uint64_t r1 = (w >> 8)  | (w << 56);
    uint64_t r2 = (w >> 16) | (w << 48);
    uint64_t r3 = (w >> 24) | (w << 40);
    uint64_t r4 = (w >> 32) | (w << 32);
    return !(haszero8(w ^ r1) | haszero8(w ^ r2) | haszero8(w ^ r3) | haszero8(w ^ r4));
}

__global__ __launch_bounds__(NT) void EntropyPatcher_kernel(
        const int* __restrict__ tokens, int* __restrict__ out) {
    // LDS budget (~43 KB):
    __shared__ uint32_t tok32[2052];        // 8192 tokens as u8, +16B zero pad
    __shared__ uint32_t stopb[258];         // stop bitmap, +2 zero words
    __shared__ uint8_t  sizes_s[SEQ];       // patch size at every position (1..16)
    __shared__ uint16_t f_s[SEQ];           // chunk DP: rel_exit (lo8) | count (hi8)
    __shared__ uint16_t starts_s[MAXP + 4]; // patch start list; starts_s[P] = SEQ
    __shared__ int      entry_s[130];       // visited-chunk entry positions
    __shared__ int      base_s[130];        // patch index base per visited chunk
    __shared__ int      P_s, nv_s;

    const int b   = blockIdx.x;
    const int tid = threadIdx.x;
    const int* tseq = tokens + (size_t)b * SEQ;

    // ---- Phase A: coalesced load, pack tokens to u8 in LDS ----
    {
        const int4* t4 = (const int4*)tseq;
        #pragma unroll
        for (int k = 0; k < 8; ++k) {
            int g = k * NT + tid;                 // 2048 int4 groups
            int4 v = t4[g];
            tok32[g] = (uint32_t)(v.x & 255) | ((uint32_t)(v.y & 255) << 8) |
                       ((uint32_t)(v.z & 255) << 16) | ((uint32_t)(v.w & 255) << 24);
        }
        if (tid < 4) tok32[2048 + tid] = 0u;
        if (tid < 2) stopb[256 + tid] = 0u;
    }
    __syncthreads();

    // ---- Phase B: stop bits. stop[j] = (j <= SEQ-8) && all 8 bytes distinct ----
    {
        const int base = tid * 8;                 // word index; byte j0 = tid*32
        const int j0 = tid * 32;
        uint64_t win = (uint64_t)tok32[base] | ((uint64_t)tok32[base + 1] << 32);
        uint32_t bits = 0;
        #pragma unroll
        for (int k = 0; k < 8; ++k) {
            uint32_t nx = tok32[base + 2 + k];    // bytes j0+8+4k .. j0+11+4k
            #pragma unroll
            for (int m = 0; m < 4; ++m) {
                int j = j0 + k * 4 + m;
                if (j <= SEQ - 8 && distinct8(win)) bits |= (1u << (k * 4 + m));
                win = (win >> 8) | ((uint64_t)(nx & 255u) << 56);
                nx >>= 8;
            }
        }
        stopb[tid] = bits;
    }
    __syncthreads();

    // ---- Phase C: sizes[i] = first stop in [i+2, i+16) else min(16, SEQ-i) ----
    {
        const int i0 = tid * 32;
        #pragma unroll 4
        for (int m = 0; m < 32; ++m) {
            int i = i0 + m;
            int bitpos = i + 2;
            int w = bitpos >> 5, o = bitpos & 31;
            uint64_t comb = (uint64_t)stopb[w] | ((uint64_t)stopb[w + 1] << 32);
            uint32_t win14 = (uint32_t)(comb >> o) & 0x3FFFu;
            int sz;
            if (win14) sz = 2 + __builtin_ctz(win14);
            else { sz = SEQ - i; if (sz > 16) sz = 16; }
            sizes_s[i] = (uint8_t)sz;
        }
    }
    __syncthreads();

    // ---- Phase D: per-chunk backward DP (chunks of 64) ----
    if (tid < 128) {
        const int cbase = tid * 64;
        const int cend  = cbase + 64;
        for (int i = cend - 1; i >= cbase; --i) {
            int j = i + (int)sizes_s[i];
            uint16_t fv;
            if (j >= cend) fv = (uint16_t)((j - cbase) | (1u << 8));
            else {
                uint16_t fj = f_s[j];
                fv = (uint16_t)((fj & 255u) | ((uint32_t)((fj >> 8) + 1u) << 8));
            }
            f_s[i] = fv;
        }
    }
    __syncthreads();

    // ---- Phase E: serial chain across chunks (<=128 steps) ----
    if (tid == 0) {
        int i = 0, pidx = 0, m = 0;
        while (i < SEQ) {
            entry_s[m] = i; base_s[m] = pidx;
            uint16_t fv = f_s[i];
            pidx += (int)(fv >> 8);
            i = (i & ~63) + (int)(fv & 255u);
            ++m;
        }
        P_s = pidx; nv_s = m;
        starts_s[pidx] = (uint16_t)SEQ;   // sentinel: sz[P-1] = SEQ - start
    }
    __syncthreads();

    // ---- Phase F: parallel expansion per visited chunk ----
    if (tid < nv_s) {
        int i = entry_s[tid];
        int p = base_s[tid];
        const int cend = (i & ~63) + 64;
        while (i < cend) {
            starts_s[p++] = (uint16_t)i;
            i += (int)sizes_s[i];
        }
    }
    __syncthreads();

    // ---- Phase G: emission (coalesced 64B per patch + mask) ----
    const int P = P_s;
    int* outp = out + (size_t)b * MAXP * 16;
    int* outm = out + (size_t)NB * MAXP * 16 + (size_t)b * MAXP;
    const uint8_t* tok8 = (const uint8_t*)tok32;
    for (int p = tid; p < MAXP; p += NT) {
        int4 o0 = make_int4(0,0,0,0), o1 = o0, o2 = o0, o3 = o0;
        int msk = 0;
        if (p < P) {
            msk = 1;
            int st = (int)starts_s[p];
            int sz = (int)starts_s[p + 1] - st;
            int t[16];
            #pragma unroll
            for (int l = 0; l < 16; ++l) t[l] = (l < sz) ? (int)tok8[st + l] : 0;
            o0 = make_int4(t[0],  t[1],  t[2],  t[3]);
            o1 = make_int4(t[4],  t[5],  t[6],  t[7]);
            o2 = make_int4(t[8],  t[9],  t[10], t[11]);
            o3 = make_int4(t[12], t[13], t[14], t[15]);
        }
        int4* dst = (int4*)(outp + (size_t)p * 16);
        dst[0] = o0; dst[1] = o1; dst[2] = o2; dst[3] = o3;
        outm[p] = msk;
    }
}

extern "C" void kernel_launch(void* const* d_in, const int* in_sizes, int n_in,
                              void* d_out, int out_size, void* d_ws, size_t ws_size,
                              hipStream_t stream) {
    const int* tokens = (const int*)d_in[0];
    int* out = (int*)d_out;
    EntropyPatcher_kernel<<<dim3(NB), dim3(NT), 0, stream>>>(tokens, out);
}

// Round 2
// 28.055 us; speedup vs baseline: 1.6491x; 1.6491x over previous
//
#include <hip/hip_runtime.h>
#include <stdint.h>

#define SEQ  8192
#define NB   128
#define MAXP 4096
#define WS_STRIDE_U32 2056                       // per-seq starts stride (4112 u16)
#define WS_NEEDED ((size_t)NB * WS_STRIDE_U32 * 4)

__device__ __forceinline__ bool haszero8(uint64_t v) {
    return ((v - 0x0101010101010101ULL) & ~v & 0x8080808080808080ULL) != 0ULL;
}
__device__ __forceinline__ bool distinct8(uint64_t w) {
    uint64_t r1 = (w >> 8)  | (w << 56);
    uint64_t r2 = (w >> 16) | (w << 48);
    uint64_t r3 = (w >> 24) | (w << 40);
    uint64_t r4 = (w >> 32) | (w << 32);
    return !(haszero8(w ^ r1) | haszero8(w ^ r2) | haszero8(w ^ r3) | haszero8(w ^ r4));
}
__device__ __forceinline__ uint32_t pack4(int4 v) {
    return (uint32_t)(v.x & 255) | ((uint32_t)(v.y & 255) << 8) |
           ((uint32_t)(v.z & 255) << 16) | ((uint32_t)(v.w & 255) << 24);
}

// ---------------- Kernel 1: per-sequence patch-start list via pointer doubling ----
__global__ __launch_bounds__(512) void ep_chain(const int* __restrict__ tokens,
                                                uint32_t* __restrict__ ws_starts) {
    __shared__ uint32_t tok32[2052];   // 8192 tokens as u8 + zero pad
    __shared__ uint32_t stopb[258];    // stop bitmap + pad
    __shared__ uint16_t Ja[8200];      // jump table ping
    __shared__ uint16_t Jb[8200];      // jump table pong
    __shared__ uint16_t A[4104];       // orbit: A[t] = pos after t steps from 0

    const int b = blockIdx.x, tid = threadIdx.x;
    const int4* t4 = (const int4*)(tokens + (size_t)b * SEQ);

    #pragma unroll
    for (int k = 0; k < 4; ++k) {
        int g = k * 512 + tid;
        tok32[g] = pack4(t4[g]);
    }
    if (tid < 4) tok32[2048 + tid] = 0u;
    if (tid < 2) stopb[256 + tid] = 0u;
    __syncthreads();

    // stop[j] = (j <= SEQ-8) && all 8 bytes of window distinct  (exact integer test)
    if (tid < 256) {
        const int base = tid * 8;
        uint64_t win = (uint64_t)tok32[base] | ((uint64_t)tok32[base + 1] << 32);
        uint32_t bits = 0;
        #pragma unroll
        for (int k = 0; k < 8; ++k) {
            uint32_t nx = tok32[base + 2 + k];
            #pragma unroll
            for (int m = 0; m < 4; ++m) {
                int j = tid * 32 + k * 4 + m;
                if (j <= SEQ - 8 && distinct8(win)) bits |= (1u << (k * 4 + m));
                win = (win >> 8) | ((uint64_t)(nx & 255u) << 56);
                nx >>= 8;
            }
        }
        stopb[tid] = bits;
    }
    __syncthreads();

    // J0[i] = i + sizes[i]; sizes[i] = first stop in [i+2,i+16) else min(16, SEQ-i)
    for (int i = tid; i < SEQ; i += 512) {
        int bp = i + 2, w = bp >> 5;
        uint64_t comb = (uint64_t)stopb[w] | ((uint64_t)stopb[w + 1] << 32);
        uint32_t win14 = (uint32_t)(comb >> (bp & 31)) & 0x3FFFu;
        int sz = win14 ? (2 + __builtin_ctz(win14)) : min(16, SEQ - i);
        Ja[i] = (uint16_t)(i + sz);
    }
    if (tid == 0) { Ja[SEQ] = SEQ; A[0] = 0; }
    __syncthreads();

    // 12 levels: expand orbit with J_k, then double J_k -> J_{k+1}
    uint16_t* cur = Ja; uint16_t* nxt = Jb;
    for (int k = 0; k < 12; ++k) {
        const int cnt = 1 << k;
        for (int t = tid; t < cnt; t += 512)
            A[t + cnt] = cur[A[t]];
        if (k < 11)
            for (int i = tid; i <= SEQ; i += 512)
                nxt[i] = cur[cur[i]];
        __syncthreads();
        uint16_t* tmp = cur; cur = nxt; nxt = tmp;
    }
    if (tid == 0) A[MAXP] = (uint16_t)SEQ;   // sentinel
    __syncthreads();

    const uint32_t* a32 = (const uint32_t*)A;
    uint32_t* dst = ws_starts + (size_t)b * WS_STRIDE_U32;
    for (int w = tid; w < 2049; w += 512) dst[w] = a32[w];
}

// ---------------- Kernel 2: coalesced emission, 8 blocks per sequence -------------
__global__ __launch_bounds__(256) void ep_emit(const int* __restrict__ tokens,
                                               const uint32_t* __restrict__ ws_starts,
                                               int* __restrict__ out) {
    __shared__ uint16_t s[520];        // 512 starts + next + pad
    __shared__ uint32_t tokw[2052];    // token span as u8 (<= 8192 tokens)

    const int b = blockIdx.x >> 3, c = blockIdx.x & 7, tid = threadIdx.x;
    const uint32_t* src = ws_starts + (size_t)b * WS_STRIDE_U32 + c * 256;
    for (int g = tid; g < 258; g += 256) ((uint32_t*)s)[g] = src[g];
    __syncthreads();

    const int base4 = (int)s[0] & ~3;
    const int end   = (int)s[512];
    const int ngrp  = (end - base4 + 3) >> 2;      // int4 groups (4 tokens each)
    const int4* t4 = (const int4*)(tokens + (size_t)b * SEQ);
    const int g0 = base4 >> 2;
    for (int g = tid; g < ngrp; g += 256) tokw[g] = pack4(t4[g0 + g]);
    __syncthreads();

    const uint8_t* tok8 = (const uint8_t*)tokw;
    int* outp = out + (size_t)b * (MAXP * 16) + (size_t)c * (512 * 16);
    const int q = tid & 3;
    #pragma unroll
    for (int it = 0; it < 8; ++it) {
        int p  = it * 64 + (tid >> 2);
        int st = (int)s[p];
        int sz = (int)s[p + 1] - st;
        int off = st - base4 + q * 4;
        int t[4];
        #pragma unroll
        for (int j = 0; j < 4; ++j) {
            int l = q * 4 + j;
            int idx = off + j; if (idx > 8207) idx = 8207;
            t[j] = (l < sz) ? (int)tok8[idx] : 0;
        }
        ((int4*)outp)[p * 4 + q] = make_int4(t[0], t[1], t[2], t[3]);
    }
    int* outm = out + (size_t)NB * MAXP * 16 + (size_t)b * MAXP + c * 512;
    for (int pm = tid; pm < 512; pm += 256)
        outm[pm] = ((int)s[pm] < SEQ) ? 1 : 0;
}

// ---------------- Fallback: proven round-1 monolithic kernel ----------------------
__global__ __launch_bounds__(256) void ep_mono(const int* __restrict__ tokens,
                                               int* __restrict__ out) {
    __shared__ uint32_t tok32[2052];
    __shared__ uint32_t stopb[258];
    __shared__ uint8_t  sizes_s[SEQ];
    __shared__ uint16_t f_s[SEQ];
    __shared__ uint16_t starts_s[MAXP + 4];
    __shared__ int      entry_s[130];
    __shared__ int      base_s[130];
    __shared__ int      P_s, nv_s;

    const int b = blockIdx.x, tid = threadIdx.x;
    const int* tseq = tokens + (size_t)b * SEQ;
    {
        const int4* t4 = (const int4*)tseq;
        #pragma unroll
        for (int k = 0; k < 8; ++k) { int g = k * 256 + tid; tok32[g] = pack4(t4[g]); }
        if (tid < 4) tok32[2048 + tid] = 0u;
        if (tid < 2) stopb[256 + tid] = 0u;
    }
    __syncthreads();
    {
        const int base = tid * 8;
        uint64_t win = (uint64_t)tok32[base] | ((uint64_t)tok32[base + 1] << 32);
        uint32_t bits = 0;
        #pragma unroll
        for (int k = 0; k < 8; ++k) {
            uint32_t nx = tok32[base + 2 + k];
            #pragma unroll
            for (int m = 0; m < 4; ++m) {
                int j = tid * 32 + k * 4 + m;
                if (j <= SEQ - 8 && distinct8(win)) bits |= (1u << (k * 4 + m));
                win = (win >> 8) | ((uint64_t)(nx & 255u) << 56);
                nx >>= 8;
            }
        }
        stopb[tid] = bits;
    }
    __syncthreads();
    {
        const int i0 = tid * 32;
        #pragma unroll 4
        for (int m = 0; m < 32; ++m) {
            int i = i0 + m, bp = i + 2, w = bp >> 5;
            uint64_t comb = (uint64_t)stopb[w] | ((uint64_t)stopb[w + 1] << 32);
            uint32_t win14 = (uint32_t)(comb >> (bp & 31)) & 0x3FFFu;
            int sz = win14 ? (2 + __builtin_ctz(win14)) : min(16, SEQ - i);
            sizes_s[i] = (uint8_t)sz;
        }
    }
    __syncthreads();
    if (tid < 128) {
        const int cbase = tid * 64, cend = cbase + 64;
        for (int i = cend - 1; i >= cbase; --i) {
            int j = i + (int)sizes_s[i];
            uint16_t fv;
            if (j >= cend) fv = (uint16_t)((j - cbase) | (1u << 8));
            else { uint16_t fj = f_s[j];
                   fv = (uint16_t)((fj & 255u) | ((uint32_t)((fj >> 8) + 1u) << 8)); }
            f_s[i] = fv;
        }
    }
    __syncthreads();
    if (tid == 0) {
        int i = 0, pidx = 0, m = 0;
        while (i < SEQ) {
            entry_s[m] = i; base_s[m] = pidx;
            uint16_t fv = f_s[i];
            pidx += (int)(fv >> 8);
            i = (i & ~63) + (int)(fv & 255u);
            ++m;
        }
        P_s = pidx; nv_s = m;
        starts_s[pidx] = (uint16_t)SEQ;
    }
    __syncthreads();
    if (tid < nv_s) {
        int i = entry_s[tid], p = base_s[tid];
        const int cend = (i & ~63) + 64;
        while (i < cend) { starts_s[p++] = (uint16_t)i; i += (int)sizes_s[i]; }
    }
    __syncthreads();
    const int P = P_s;
    int* outp = out + (size_t)b * MAXP * 16;
    int* outm = out + (size_t)NB * MAXP * 16 + (size_t)b * MAXP;
    const uint8_t* tok8 = (const uint8_t*)tok32;
    for (int p = tid; p < MAXP; p += 256) {
        int4 o0 = make_int4(0,0,0,0), o1 = o0, o2 = o0, o3 = o0;
        int msk = 0;
        if (p < P) {
            msk = 1;
            int st = (int)starts_s[p];
            int sz = (int)starts_s[p + 1] - st;
            int t[16];
            #pragma unroll
            for (int l = 0; l < 16; ++l) t[l] = (l < sz) ? (int)tok8[st + l] : 0;
            o0 = make_int4(t[0],t[1],t[2],t[3]);   o1 = make_int4(t[4],t[5],t[6],t[7]);
            o2 = make_int4(t[8],t[9],t[10],t[11]); o3 = make_int4(t[12],t[13],t[14],t[15]);
        }
        int4* dst = (int4*)(outp + (size_t)p * 16);
        dst[0] = o0; dst[1] = o1; dst[2] = o2; dst[3] = o3;
        outm[p] = msk;
    }
}

extern "C" void kernel_launch(void* const* d_in, const int* in_sizes, int n_in,
                              void* d_out, int out_size, void* d_ws, size_t ws_size,
                              hipStream_t stream) {
    const int* tokens = (const int*)d_in[0];
    int* out = (int*)d_out;
    if (ws_size >= WS_NEEDED) {
        uint32_t* ws_starts = (uint32_t*)d_ws;
        ep_chain<<<dim3(NB), dim3(512), 0, stream>>>(tokens, ws_starts);
        ep_emit<<<dim3(NB * 8), dim3(256), 0, stream>>>(tokens, ws_starts, out);
    } else {
        ep_mono<<<dim3(NB), dim3(256), 0, stream>>>(tokens, out);
    }
}